// Round 1
// baseline (3241.364 us; speedup 1.0000x reference)
//
#include <hip/hip_runtime.h>
#include <math.h>

// ===========================================================================
// CrossAttentionLayer — collapsed form.
//
// Key algebraic fact: kv is broadcast_to(kv_row) over the j axis, so every
// key/value row is identical per batch. softmax over identical scores is
// exactly uniform (1/64), and sum_j (1/64) v_row = v_row. The attention
// output is independent of q:
//   attn_out[b,c] = sum_{h=0..7} sum_{d=0..63} v_row[b,d] * Wout[h*64+d, c]
// where v_row[b,:] = (LN(extra_info[b]) @ Wkv)[64:128].
// Wq is never needed. The per-position work is only:
//   x = LN_C(cnn[b,:,m,n]);  h = x@W1;  ff = (silu(h[512:])*h[:512])@W2
//   out[b,c,m,n] = attn_out[b,c] + ff[c]
// ===========================================================================

#define BATCH  16
#define C_DIM  256
#define HW     4096   // 64*64 spatial positions per batch
#define EDIM   512
#define FFI    512    // FF_INNER

// ---------------------------------------------------------------------------
// Kernel 1: per-batch collapsed attention contribution (16 x 256). Trivial.
// ---------------------------------------------------------------------------
__global__ void attn_rows_kernel(const float* __restrict__ extra,   // (16,512)
                                 const float* __restrict__ ln2_g,   // (512)
                                 const float* __restrict__ ln2_b,   // (512)
                                 const float* __restrict__ Wkv,     // (512,128)
                                 const float* __restrict__ Wout,    // (512,256)
                                 float* __restrict__ attn_out)      // (16,256)
{
    __shared__ float e[512];
    __shared__ float red[256];
    __shared__ float red2[256];
    __shared__ float vrow[64];
    const int b = blockIdx.x;
    const int t = threadIdx.x;  // 256 threads

    float a0 = extra[b * 512 + t];
    float a1 = extra[b * 512 + 256 + t];
    e[t] = a0;
    e[t + 256] = a1;
    red[t] = a0 + a1;
    red2[t] = a0 * a0 + a1 * a1;
    __syncthreads();
    for (int off = 128; off; off >>= 1) {
        if (t < off) { red[t] += red[t + off]; red2[t] += red2[t + off]; }
        __syncthreads();
    }
    const float mean = red[0] * (1.0f / 512.0f);
    const float var  = red2[0] * (1.0f / 512.0f) - mean * mean;
    const float rs   = rsqrtf(var + 1e-5f);
    // normalize (each thread owns e[t], e[t+256])
    e[t]       = (e[t]       - mean) * rs * ln2_g[t]       + ln2_b[t];
    e[t + 256] = (e[t + 256] - mean) * rs * ln2_g[t + 256] + ln2_b[t + 256];
    __syncthreads();
    // v_row[d] = sum_i e[i] * Wkv[i, 64+d]
    if (t < 64) {
        float acc = 0.0f;
        for (int i = 0; i < 512; ++i) acc += e[i] * Wkv[i * 128 + 64 + t];
        vrow[t] = acc;
    }
    __syncthreads();
    // attn_out[b,c] = sum_{i=0..511} vrow[i&63] * Wout[i, c]
    float acc = 0.0f;
    for (int i = 0; i < 512; ++i) acc += vrow[i & 63] * Wout[i * 256 + t];
    attn_out[b * 256 + t] = acc;
}

// ---------------------------------------------------------------------------
// Kernel 2: main. 64 spatial positions per block, 256 threads.
//   thread t: p = t&63 (position), q = t>>6 (quarter: channel/k/c sub-range)
// Phases: load+LN (LDS xs[256][64]) -> 8 chunks of {W1 dots -> silu-gate ->
//   val[64][64] in LDS -> W2 accumulation into 64 regs} -> write out.
// ---------------------------------------------------------------------------
__global__ void main_kernel(const float* __restrict__ cnn,      // (16,256,64,64)
                            const float* __restrict__ ln1_g,    // (256)
                            const float* __restrict__ ln1_b,    // (256)
                            const float* __restrict__ W1,       // (256,1024)
                            const float* __restrict__ W2,       // (512,256)
                            const float* __restrict__ attn_out, // (16,256)
                            float* __restrict__ out)            // (16,256,64,64)
{
    __shared__ float xs[C_DIM * 64];   // 64 KiB: normalized x, [c][p]
    __shared__ float val[64 * 64];     // 16 KiB: silu(gate)*xh, [k_local][p]

    const int t  = threadIdx.x;
    const int b  = blockIdx.x >> 6;          // 64 blocks per batch
    const int p0 = (blockIdx.x & 63) << 6;   // 64 positions per block
    const int p  = t & 63;
    const int q  = t >> 6;

    const float* cb = cnn + (size_t)b * C_DIM * HW + p0 + p;

    // ---- load (coalesced along spatial) + per-strip partial sums ----
    float s = 0.0f, s2 = 0.0f;
    for (int i = 0; i < 64; ++i) {
        const int c = q * 64 + i;
        float x = cb[(size_t)c * HW];
        xs[c * 64 + p] = x;
        s += x; s2 += x * x;
    }
    val[q * 64 + p] = s;
    val[256 + q * 64 + p] = s2;
    __syncthreads();

    if (t < 64) {
        float ssum = val[t] + val[64 + t] + val[128 + t] + val[192 + t];
        float sq   = val[256 + t] + val[320 + t] + val[384 + t] + val[448 + t];
        float mean = ssum * (1.0f / 256.0f);
        float var  = sq * (1.0f / 256.0f) - mean * mean;
        val[512 + t] = mean;
        val[576 + t] = rsqrtf(var + 1e-5f);
    }
    __syncthreads();

    {
        const float mean = val[512 + p];
        const float rs   = val[576 + p];
        for (int i = 0; i < 64; ++i) {
            const int c = q * 64 + i;
            xs[c * 64 + p] = (xs[c * 64 + p] - mean) * rs * ln1_g[c] + ln1_b[c];
        }
    }
    __syncthreads();

    // ---- FF: out_ff[p][c] = sum_k silu(gate[p,k])*xh[p,k] * W2[k,c] ----
    float acc[64];
#pragma unroll
    for (int i = 0; i < 64; ++i) acc[i] = 0.0f;

    for (int kc = 0; kc < 8; ++kc) {
        // phase 1: this thread computes xh/gate for k = k0..k0+15 at position p
        const int k0 = kc * 64 + q * 16;
        float axh[16], ag[16];
#pragma unroll
        for (int j = 0; j < 16; ++j) { axh[j] = 0.0f; ag[j] = 0.0f; }

        for (int c = 0; c < 256; ++c) {
            const float x = xs[c * 64 + p];
            const float4* w1a = reinterpret_cast<const float4*>(W1 + c * 1024 + k0);
            const float4* w1b = reinterpret_cast<const float4*>(W1 + c * 1024 + 512 + k0);
#pragma unroll
            for (int j4 = 0; j4 < 4; ++j4) {
                const float4 wa = w1a[j4];
                const float4 wb = w1b[j4];
                axh[j4 * 4 + 0] += x * wa.x;
                axh[j4 * 4 + 1] += x * wa.y;
                axh[j4 * 4 + 2] += x * wa.z;
                axh[j4 * 4 + 3] += x * wa.w;
                ag[j4 * 4 + 0] += x * wb.x;
                ag[j4 * 4 + 1] += x * wb.y;
                ag[j4 * 4 + 2] += x * wb.z;
                ag[j4 * 4 + 3] += x * wb.w;
            }
        }

        __syncthreads();  // previous chunk's phase-2 readers are done with val
#pragma unroll
        for (int j = 0; j < 16; ++j) {
            const float g  = ag[j];
            const float sv = g / (1.0f + __expf(-g));   // silu(g)
            val[(q * 16 + j) * 64 + p] = sv * axh[j];
        }
        __syncthreads();

        // phase 2: accumulate into out_ff[p][q*64 .. q*64+63]
        for (int kl = 0; kl < 64; ++kl) {
            const float v = val[kl * 64 + p];
            const float4* w2v = reinterpret_cast<const float4*>(
                W2 + (size_t)(kc * 64 + kl) * 256 + q * 64);
#pragma unroll
            for (int j4 = 0; j4 < 16; ++j4) {
                const float4 w = w2v[j4];
                acc[j4 * 4 + 0] += v * w.x;
                acc[j4 * 4 + 1] += v * w.y;
                acc[j4 * 4 + 2] += v * w.z;
                acc[j4 * 4 + 3] += v * w.w;
            }
        }
    }

    // ---- write out[b, c, p0+p] = acc + attn_out[b, c] ----
    const float* ab = attn_out + b * 256;
    float* ob = out + (size_t)b * C_DIM * HW + p0 + p;
#pragma unroll
    for (int cc = 0; cc < 64; ++cc) {
        const int c = q * 64 + cc;
        ob[(size_t)c * HW] = acc[cc] + ab[c];
    }
}

// ---------------------------------------------------------------------------
extern "C" void kernel_launch(void* const* d_in, const int* in_sizes, int n_in,
                              void* d_out, int out_size, void* d_ws, size_t ws_size,
                              hipStream_t stream) {
    const float* cnn   = (const float*)d_in[0];   // (16,256,64,64)
    const float* extra = (const float*)d_in[1];   // (16,512)
    const float* ln1_g = (const float*)d_in[2];
    const float* ln1_b = (const float*)d_in[3];
    const float* ln2_g = (const float*)d_in[4];
    const float* ln2_b = (const float*)d_in[5];
    // d_in[6] = Wq  — provably unused (attention output independent of q)
    const float* Wkv   = (const float*)d_in[7];   // (512,128)
    const float* Wout  = (const float*)d_in[8];   // (512,256)
    const float* W1    = (const float*)d_in[9];   // (256,1024)
    const float* W2    = (const float*)d_in[10];  // (512,256)
    float* out = (float*)d_out;

    float* attn_out = (float*)d_ws;               // 16*256 floats = 16 KiB

    attn_rows_kernel<<<BATCH, 256, 0, stream>>>(extra, ln2_g, ln2_b, Wkv, Wout, attn_out);
    main_kernel<<<BATCH * 64, 256, 0, stream>>>(cnn, ln1_g, ln1_b, W1, W2, attn_out, out);
}

// Round 2
// 169.611 us; speedup vs baseline: 19.1106x; 19.1106x over previous
//
#include <hip/hip_runtime.h>
#include <math.h>

// ===========================================================================
// CrossAttentionLayer — collapsed attention + bf16-MFMA SwiGLU FF.
//
// Attention collapses (kv broadcast => softmax uniform => out = v_row):
//   attn_out[b,c] = sum_i vrow[b, i&63] * Wout[i,c],
//   vrow[b,:] = (LN(extra[b]) @ Wkv)[64:128].   Wq unused.
// Per-position work: x = LN_C(cnn); h = x@W1; ff = (silu(h[:,512:])*h[:,:512])@W2
//   out[b,c,p] = attn_out[b,c] + ff[p,c]
// FF done with mfma_f32_16x16x32_bf16: A = x (pos x chan) from swizzled LDS,
// B = W^T bf16 (precomputed by prep kernel) read直接 from L2.
// ===========================================================================

#define BATCH 16
#define CDIM  256
#define HW    4096
#define FFI   512

using short8 = __attribute__((ext_vector_type(8))) short;
using f32x4  = __attribute__((ext_vector_type(4))) float;
typedef unsigned int   u32;
typedef unsigned short u16;

__device__ __forceinline__ u16 f2bf(float f) {
    u32 u = __float_as_uint(f);
    u += 0x7fffu + ((u >> 16) & 1u);   // round-nearest-even
    return (u16)(u >> 16);
}

// ---------------------------------------------------------------------------
// Prep: blocks 0..15  -> collapsed attention rows (16 x 256 f32)
//       blocks 16..79 -> W1 (256x1024) -> W1^T bf16 (1024x256)
//       blocks 80..111-> W2 (512x256)  -> W2^T bf16 (256x512)
// ---------------------------------------------------------------------------
__global__ void prep_kernel(const float* __restrict__ extra,
                            const float* __restrict__ ln2_g,
                            const float* __restrict__ ln2_b,
                            const float* __restrict__ Wkv,
                            const float* __restrict__ Wout,
                            const float* __restrict__ W1,
                            const float* __restrict__ W2,
                            float* __restrict__ attn_out,
                            u16* __restrict__ w1t,
                            u16* __restrict__ w2t)
{
    const int t = threadIdx.x;
    if (blockIdx.x < BATCH) {
        __shared__ float e[512];
        __shared__ float red[256], red2[256];
        __shared__ float vpart[256];
        __shared__ float vrow[64];
        const int b = blockIdx.x;
        float a0 = extra[b * 512 + t];
        float a1 = extra[b * 512 + 256 + t];
        e[t] = a0; e[t + 256] = a1;
        red[t] = a0 + a1; red2[t] = a0 * a0 + a1 * a1;
        __syncthreads();
        for (int off = 128; off; off >>= 1) {
            if (t < off) { red[t] += red[t + off]; red2[t] += red2[t + off]; }
            __syncthreads();
        }
        const float mean = red[0] * (1.0f / 512.0f);
        const float var  = red2[0] * (1.0f / 512.0f) - mean * mean;
        const float rs   = rsqrtf(var + 1e-5f);
        e[t]       = (e[t]       - mean) * rs * ln2_g[t]       + ln2_b[t];
        e[t + 256] = (e[t + 256] - mean) * rs * ln2_g[t + 256] + ln2_b[t + 256];
        __syncthreads();
        {   // vrow[d] = sum_i e[i]*Wkv[i,64+d], split over 4 i-parts
            const int d = t & 63, part = t >> 6;
            float acc = 0.0f;
            for (int i = part * 128; i < part * 128 + 128; ++i)
                acc += e[i] * Wkv[i * 128 + 64 + d];
            vpart[t] = acc;
        }
        __syncthreads();
        if (t < 64) vrow[t] = vpart[t] + vpart[t + 64] + vpart[t + 128] + vpart[t + 192];
        __syncthreads();
        float acc = 0.0f;
        for (int i = 0; i < 512; ++i) acc += vrow[i & 63] * Wout[i * 256 + t];
        attn_out[b * 256 + t] = acc;
    } else {
        __shared__ float tile[64][65];   // +1 pad: conflict-free transposed read
        int id = blockIdx.x - BATCH;
        const float* src; u16* dst; int Rr, Cc, tr, tc;
        if (id < 64) { src = W1; dst = w1t; Rr = 256; Cc = 1024; tr = id >> 4; tc = id & 15; }
        else { id -= 64; src = W2; dst = w2t; Rr = 512; Cc = 256; tr = id >> 2; tc = id & 3; }
        const int rl = t >> 6, col = t & 63;
#pragma unroll
        for (int i = 0; i < 16; ++i) {
            int r = i * 4 + rl;
            tile[r][col] = src[(size_t)(tr * 64 + r) * Cc + tc * 64 + col];
        }
        __syncthreads();
#pragma unroll
        for (int i = 0; i < 16; ++i) {
            int n = i * 4 + rl;
            dst[(size_t)(tc * 64 + n) * Rr + tr * 64 + col] = f2bf(tile[col][n]);
        }
    }
}

// ---------------------------------------------------------------------------
// Main: 64 positions per block (1024 blocks), 4 waves.
// ---------------------------------------------------------------------------
__global__ void __launch_bounds__(256) main_kernel(
    const float* __restrict__ cnn,      // (16,256,64,64)
    const float* __restrict__ ln1_g,
    const float* __restrict__ ln1_b,
    const u16*  __restrict__ w1t,       // (1024,256) bf16: row n, col c
    const u16*  __restrict__ w2t,       // (256,512)  bf16: row c, col k
    const float* __restrict__ attn_out, // (16,256)
    float* __restrict__ out)            // (16,256,64,64)
{
    __shared__ u16  xs[64 * 256];   // 32 KiB, swizzled [p][c]
    __shared__ u16  val[64 * 128];  // 16 KiB, swizzled [p][k]
    __shared__ float red[640];

    const int t  = threadIdx.x;
    const int b  = blockIdx.x >> 6;
    const int p0 = (blockIdx.x & 63) << 6;
    const int p  = t & 63;
    const int q  = t >> 6;          // wave id == channel-quarter
    const int lane = t & 63;
    const int l15  = lane & 15;
    const int lg   = lane >> 4;

    // ---- load cnn (coalesced along p) + LN stats from registers ----
    const float* cb = cnn + (size_t)b * CDIM * HW + p0 + p;
    float v[64];
    float s = 0.0f, s2 = 0.0f;
#pragma unroll
    for (int i = 0; i < 64; ++i) {
        float x = cb[(size_t)(q * 64 + i) * HW];
        v[i] = x; s += x; s2 += x * x;
    }
    red[q * 64 + p] = s;
    red[256 + q * 64 + p] = s2;
    __syncthreads();
    if (t < 64) {
        float ss = red[t] + red[64 + t] + red[128 + t] + red[192 + t];
        float sq = red[256 + t] + red[320 + t] + red[384 + t] + red[448 + t];
        float mean = ss * (1.0f / 256.0f);
        float var  = sq * (1.0f / 256.0f) - mean * mean;
        red[512 + t] = mean;
        red[576 + t] = rsqrtf(var + 1e-5f);
    }
    __syncthreads();
    {   // normalize + bf16 + swizzled LDS write (packed pairs)
        const float mean = red[512 + p], rs = red[576 + p];
#pragma unroll
        for (int i = 0; i < 32; ++i) {
            int c = q * 64 + 2 * i;
            float x0 = (v[2 * i]     - mean) * rs * ln1_g[c]     + ln1_b[c];
            float x1 = (v[2 * i + 1] - mean) * rs * ln1_g[c + 1] + ln1_b[c + 1];
            u32 pk = (u32)f2bf(x0) | ((u32)f2bf(x1) << 16);
            int chunk = (c >> 3) ^ (p & 7);
            *(u32*)((char*)xs + p * 512 + chunk * 16 + (i & 3) * 4) = pk;
        }
    }
    __syncthreads();

    // ---- FF with MFMA ----
    f32x4 acc2[4][4];
#pragma unroll
    for (int n = 0; n < 4; ++n)
#pragma unroll
        for (int m = 0; m < 4; ++m)
            acc2[n][m] = (f32x4){0.0f, 0.0f, 0.0f, 0.0f};

    for (int kc = 0; kc < 4; ++kc) {   // FFI chunk of 128 (wave owns 32 cols)
        f32x4 axh[2][4], ag[2][4];
#pragma unroll
        for (int n = 0; n < 2; ++n)
#pragma unroll
            for (int m = 0; m < 4; ++m) {
                axh[n][m] = (f32x4){0.0f, 0.0f, 0.0f, 0.0f};
                ag[n][m]  = (f32x4){0.0f, 0.0f, 0.0f, 0.0f};
            }
        const int nb = kc * 128 + q * 32;   // W1T row base (xh); +512 = gate
#pragma unroll
        for (int ks = 0; ks < 8; ++ks) {    // K = 256, 32 per step
            short8 a[4];
#pragma unroll
            for (int m = 0; m < 4; ++m) {
                int row = m * 16 + l15;
                int chunk = (ks * 4 + lg) ^ (row & 7);
                a[m] = *(const short8*)((const char*)xs + row * 512 + chunk * 16);
            }
            short8 bx[2], bg[2];
#pragma unroll
            for (int n = 0; n < 2; ++n) {
                bx[n] = *(const short8*)(w1t + (size_t)(nb + n * 16 + l15) * 256 + ks * 32 + lg * 8);
                bg[n] = *(const short8*)(w1t + (size_t)(512 + nb + n * 16 + l15) * 256 + ks * 32 + lg * 8);
            }
#pragma unroll
            for (int n = 0; n < 2; ++n)
#pragma unroll
                for (int m = 0; m < 4; ++m) {
                    axh[n][m] = __builtin_amdgcn_mfma_f32_16x16x32_bf16(a[m], bx[n], axh[n][m], 0, 0, 0);
                    ag[n][m]  = __builtin_amdgcn_mfma_f32_16x16x32_bf16(a[m], bg[n], ag[n][m], 0, 0, 0);
                }
        }
        // silu(gate)*xh -> bf16 -> swizzled val (prev GEMM2 finished at loop-end sync)
#pragma unroll
        for (int n = 0; n < 2; ++n)
#pragma unroll
            for (int m = 0; m < 4; ++m)
#pragma unroll
                for (int j = 0; j < 4; ++j) {
                    float g  = ag[n][m][j];
                    float sv = (g / (1.0f + __expf(-g))) * axh[n][m][j];
                    int row  = m * 16 + lg * 4 + j;
                    int kcol = q * 32 + n * 16 + l15;
                    int chunk = (kcol >> 3) ^ (row & 7);
                    *(u16*)((char*)val + row * 256 + chunk * 16 + (kcol & 7) * 2) = f2bf(sv);
                }
        __syncthreads();
        // GEMM2: acc2 += val(64x128) @ W2T-chunk; wave owns 64 out channels
#pragma unroll
        for (int ks = 0; ks < 4; ++ks) {
            short8 a2[4], b2[4];
#pragma unroll
            for (int m = 0; m < 4; ++m) {
                int row = m * 16 + l15;
                int chunk = (ks * 4 + lg) ^ (row & 7);
                a2[m] = *(const short8*)((const char*)val + row * 256 + chunk * 16);
            }
#pragma unroll
            for (int n = 0; n < 4; ++n)
                b2[n] = *(const short8*)(w2t + (size_t)(q * 64 + n * 16 + l15) * 512 + kc * 128 + ks * 32 + lg * 8);
#pragma unroll
            for (int n = 0; n < 4; ++n)
#pragma unroll
                for (int m = 0; m < 4; ++m)
                    acc2[n][m] = __builtin_amdgcn_mfma_f32_16x16x32_bf16(a2[m], b2[n], acc2[n][m], 0, 0, 0);
        }
        __syncthreads();
    }

    // ---- epilogue: + attn row, float4 stores (4 consecutive positions/lane) ----
    float att[4];
#pragma unroll
    for (int n = 0; n < 4; ++n) att[n] = attn_out[b * 256 + q * 64 + n * 16 + l15];
    float* ob = out + (size_t)b * CDIM * HW;
#pragma unroll
    for (int n = 0; n < 4; ++n) {
        int c = q * 64 + n * 16 + l15;
#pragma unroll
        for (int m = 0; m < 4; ++m) {
            f32x4 r = acc2[n][m];
            r[0] += att[n]; r[1] += att[n]; r[2] += att[n]; r[3] += att[n];
            *(f32x4*)(ob + (size_t)c * HW + p0 + m * 16 + lg * 4) = r;
        }
    }
}

// ---------------------------------------------------------------------------
extern "C" void kernel_launch(void* const* d_in, const int* in_sizes, int n_in,
                              void* d_out, int out_size, void* d_ws, size_t ws_size,
                              hipStream_t stream) {
    const float* cnn   = (const float*)d_in[0];
    const float* extra = (const float*)d_in[1];
    const float* ln1_g = (const float*)d_in[2];
    const float* ln1_b = (const float*)d_in[3];
    const float* ln2_g = (const float*)d_in[4];
    const float* ln2_b = (const float*)d_in[5];
    // d_in[6] = Wq — provably unused
    const float* Wkv   = (const float*)d_in[7];
    const float* Wout  = (const float*)d_in[8];
    const float* W1    = (const float*)d_in[9];
    const float* W2    = (const float*)d_in[10];
    float* out = (float*)d_out;

    char* ws = (char*)d_ws;
    float* attn_out = (float*)ws;                          // 16 KiB
    u16*   w1t      = (u16*)(ws + 16 * 1024);              // 512 KiB
    u16*   w2t      = (u16*)(ws + 16 * 1024 + 512 * 1024); // 256 KiB

    prep_kernel<<<112, 256, 0, stream>>>(extra, ln2_g, ln2_b, Wkv, Wout, W1, W2,
                                         attn_out, w1t, w2t);
    main_kernel<<<BATCH * 64, 256, 0, stream>>>(cnn, ln1_g, ln1_b, w1t, w2t,
                                                attn_out, out);
}